// Round 1
// baseline (236.891 us; speedup 1.0000x reference)
//
#include <hip/hip_runtime.h>
#include <hip/hip_bf16.h>
#include <stdint.h>
#include <stddef.h>

#define B_ 8
#define S_ 2048
#define D_ 256
#define NROWS (B_ * S_)  // 16384

typedef __attribute__((ext_vector_type(8))) short short8;
typedef __attribute__((ext_vector_type(4))) short short4v;
typedef __attribute__((ext_vector_type(4))) float f32x4;

// round-to-nearest-even fp32 -> bf16 bit pattern
__device__ __forceinline__ short bf16of(float f) {
  union { float f; unsigned u; } x; x.f = f;
  unsigned r = x.u + 0x7FFFu + ((x.u >> 16) & 1u);
  return (short)(r >> 16);
}

// ---------------- K0: UT[n][k] = bf16(U[k][n]) ----------------
__global__ void k_prep_u(const float* __restrict__ U, short* __restrict__ UT) {
  int n = blockIdx.x;
  int k = threadIdx.x;
  UT[n * D_ + k] = bf16of(U[k * D_ + n]);
}

// ---- K_rows: hs = head@wh, ds = dep@wd (fp32 exact); headB/depB = bf16(X) ----
// grid (4096, 2), block 256 (4 waves, 1 row per wave)
__global__ void k_rows(const float* __restrict__ head, const float* __restrict__ dep,
                       const float* __restrict__ W,
                       float* __restrict__ hs, float* __restrict__ ds,
                       short* __restrict__ headB, short* __restrict__ depB) {
  const float* X; const float* wv; float* sv; short* XB;
  if (blockIdx.y == 0) { X = head; wv = W;      sv = hs; XB = headB; }
  else                 { X = dep;  wv = W + D_; sv = ds; XB = depB;  }
  const int row = blockIdx.x * 4 + (threadIdx.x >> 6);
  const int l = threadIdx.x & 63;
  const float4 v  = *(const float4*)(X + (size_t)row * D_ + l * 4);
  const float4 wq = *(const float4*)(wv + l * 4);
  short4v pk;
  pk[0] = bf16of(v.x); pk[1] = bf16of(v.y); pk[2] = bf16of(v.z); pk[3] = bf16of(v.w);
  *(short4v*)(XB + (size_t)row * D_ + l * 4) = pk;
  float p = v.x * wq.x + v.y * wq.y + v.z * wq.z + v.w * wq.w;
  p += __shfl_xor(p, 1); p += __shfl_xor(p, 2); p += __shfl_xor(p, 4);
  p += __shfl_xor(p, 8); p += __shfl_xor(p, 16); p += __shfl_xor(p, 32);
  if (l == 0) sv[row] = p;
}

// ---------------- K1: Ahat = headB @ U (bf16) — de-staged, direct L2 fragment loads ----------------
// grid (2, 128): x = U-col tile (nbase), y = flat row tile (mbase)
// No LDS, no barriers: UT is L2-resident (128 KB), headB streamed once; fragment
// = 16B/lane direct global_load_dwordx4 (16 rows x 64B half-lines, next k-step hits other half-line).
__launch_bounds__(256, 3)
__global__ void k_ahat(const short* __restrict__ headB, const short* __restrict__ UT,
                       short* __restrict__ Ahat) {
  const int t = threadIdx.x;
  const int w = t >> 6;
  const int l = t & 63;
  const int quad = l >> 4;
  const int r15 = l & 15;
  const int nbase = blockIdx.x * 128;
  const int mbase = blockIdx.y * 128;

  const short* pA = UT + (size_t)(nbase + (w >> 1) * 64 + r15) * D_ + quad * 8;
  const short* pB = headB + (size_t)(mbase + (w & 1) * 64 + r15) * D_ + quad * 8;

  f32x4 acc[4][4];
#pragma unroll
  for (int i = 0; i < 4; ++i)
#pragma unroll
    for (int j = 0; j < 4; ++j) acc[i][j] = (f32x4)0.0f;

#pragma unroll 2
  for (int k0 = 0; k0 < D_; k0 += 32) {
    short8 aF[4], bF[4];
#pragma unroll
    for (int mt = 0; mt < 4; ++mt)
      aF[mt] = *(const short8*)(pA + (size_t)(mt * 16) * D_ + k0);
#pragma unroll
    for (int nt = 0; nt < 4; ++nt)
      bF[nt] = *(const short8*)(pB + (size_t)(nt * 16) * D_ + k0);
#pragma unroll
    for (int mt = 0; mt < 4; ++mt)
#pragma unroll
      for (int nt = 0; nt < 4; ++nt)
        acc[mt][nt] = __builtin_amdgcn_mfma_f32_16x16x32_bf16(aF[mt], bF[nt], acc[mt][nt], 0, 0, 0);
  }

  // D[m=n_col][n=i] -> lane holds 4 consecutive n_col for fixed i: short4 stores
#pragma unroll
  for (int mt = 0; mt < 4; ++mt) {
    int n_loc = (w >> 1) * 64 + mt * 16 + quad * 4;
#pragma unroll
    for (int nt = 0; nt < 4; ++nt) {
      int i_loc = (w & 1) * 64 + nt * 16 + r15;
      short4v pk;
      pk[0] = bf16of(acc[mt][nt][0]); pk[1] = bf16of(acc[mt][nt][1]);
      pk[2] = bf16of(acc[mt][nt][2]); pk[3] = bf16of(acc[mt][nt][3]);
      *(short4v*)(Ahat + (size_t)(mbase + i_loc) * D_ + nbase + n_loc) = pk;
    }
  }
}

// ------- K2: out[b,i,o] = sum_k Ahat[b,i,k] depB[b,o,k] + hs[i] + ds[o] + bias -------
// grid (16 o-tiles, 16 i-tiles, 8 b); A-operand = depB (m = o), B-operand = Ahat (n = i)
// De-staged: Ahat/depB are LLC-resident (8 MB each); depB x-slice is XCD-L2-local
// (y-stride 16 == 0 mod 8 XCDs). Zero LDS, zero barriers, no bank conflicts.
__launch_bounds__(256, 3)
__global__ void k_main(const short* __restrict__ Ahat, const short* __restrict__ depB,
                       const float* __restrict__ hs, const float* __restrict__ ds,
                       const float* __restrict__ eb, float* __restrict__ out) {
  const int t = threadIdx.x;
  const int w = t >> 6;
  const int l = t & 63;
  const int quad = l >> 4;
  const int r15 = l & 15;
  const int b = blockIdx.z;
  const int mbase = blockIdx.y * 128;  // i
  const int nbase = blockIdx.x * 128;  // o

  const short* pA = depB + (size_t)(b * S_ + nbase + (w >> 1) * 64 + r15) * D_ + quad * 8;
  const short* pB = Ahat + (size_t)(b * S_ + mbase + (w & 1) * 64 + r15) * D_ + quad * 8;

  f32x4 acc[4][4];
#pragma unroll
  for (int i = 0; i < 4; ++i)
#pragma unroll
    for (int j = 0; j < 4; ++j) acc[i][j] = (f32x4)0.0f;

#pragma unroll 2
  for (int k0 = 0; k0 < D_; k0 += 32) {
    short8 aF[4], bF[4];
#pragma unroll
    for (int mt = 0; mt < 4; ++mt)  // A-operand: dep rows (o)
      aF[mt] = *(const short8*)(pA + (size_t)(mt * 16) * D_ + k0);
#pragma unroll
    for (int nt = 0; nt < 4; ++nt)  // B-operand: Ahat rows (i)
      bF[nt] = *(const short8*)(pB + (size_t)(nt * 16) * D_ + k0);
#pragma unroll
    for (int mt = 0; mt < 4; ++mt)
#pragma unroll
      for (int nt = 0; nt < 4; ++nt)
        acc[mt][nt] = __builtin_amdgcn_mfma_f32_16x16x32_bf16(aF[mt], bF[nt], acc[mt][nt], 0, 0, 0);
  }

  const float bias = eb[0];
  float hv4[4];
#pragma unroll
  for (int nt = 0; nt < 4; ++nt)
    hv4[nt] = hs[(size_t)b * S_ + mbase + (w & 1) * 64 + nt * 16 + r15] + bias;

#pragma unroll
  for (int mt = 0; mt < 4; ++mt) {
    int o_loc = (w >> 1) * 64 + mt * 16 + quad * 4;
    float4 dsv = *(const float4*)(ds + (size_t)b * S_ + nbase + o_loc);
#pragma unroll
    for (int nt = 0; nt < 4; ++nt) {
      int i_loc = (w & 1) * 64 + nt * 16 + r15;
      float hv = hv4[nt];
      f32x4 a = acc[mt][nt];
      float4 o4;
      o4.x = a[0] + hv + dsv.x;
      o4.y = a[1] + hv + dsv.y;
      o4.z = a[2] + hv + dsv.z;
      o4.w = a[3] + hv + dsv.w;
      *(float4*)(out + (size_t)(b * S_ + mbase + i_loc) * S_ + nbase + o_loc) = o4;
    }
  }
}

extern "C" void kernel_launch(void* const* d_in, const int* in_sizes, int n_in,
                              void* d_out, int out_size, void* d_ws, size_t ws_size,
                              hipStream_t stream) {
  const float* head = (const float*)d_in[0];
  const float* dep  = (const float*)d_in[1];
  const float* U    = (const float*)d_in[2];
  const float* W    = (const float*)d_in[3];  // (1, 512): wh | wd
  const float* eb   = (const float*)d_in[4];
  float* out = (float*)d_out;

  char* ws = (char*)d_ws;
  short* UT    = (short*)ws;                       // 256*256*2     = 128 KB
  float* hs    = (float*)(ws + (128 << 10));       // 16384*4       = 64 KB
  float* ds    = (float*)(ws + (192 << 10));       // 16384*4       = 64 KB
  short* headB = (short*)(ws + (256 << 10));       // 16384*256*2   = 8 MB
  short* depB  = (short*)(ws + (256 << 10) + (8 << 20));
  short* Ahat  = (short*)(ws + (256 << 10) + (16 << 20));

  k_prep_u<<<dim3(256), dim3(256), 0, stream>>>(U, UT);
  k_rows<<<dim3(NROWS / 4, 2), dim3(256), 0, stream>>>(head, dep, W, hs, ds, headB, depB);
  k_ahat<<<dim3(2, 128), dim3(256), 0, stream>>>(headB, UT, Ahat);
  k_main<<<dim3(16, 16, 8), dim3(256), 0, stream>>>(Ahat, depB, hs, ds, eb, out);
}

// Round 2
// 194.040 us; speedup vs baseline: 1.2208x; 1.2208x over previous
//
#include <hip/hip_runtime.h>
#include <hip/hip_bf16.h>
#include <stdint.h>
#include <stddef.h>

#define B_ 8
#define S_ 2048
#define D_ 256
#define NROWS (B_ * S_)  // 16384

typedef __attribute__((ext_vector_type(8))) short short8;
typedef __attribute__((ext_vector_type(4))) short short4v;
typedef __attribute__((ext_vector_type(4))) float f32x4;

// round-to-nearest-even fp32 -> bf16 bit pattern
__device__ __forceinline__ short bf16of(float f) {
  union { float f; unsigned u; } x; x.f = f;
  unsigned r = x.u + 0x7FFFu + ((x.u >> 16) & 1u);
  return (short)(r >> 16);
}

// async global->LDS, 16B per lane (wave-uniform base + lane*16 layout)
__device__ __forceinline__ void async_ld16(const void* g, void* s) {
  __builtin_amdgcn_global_load_lds(
      (const __attribute__((address_space(1))) void*)g,
      (__attribute__((address_space(3))) void*)s, 16, 0, 0);
}

// Stage one 128x64 bf16 tile (16 KB = 1024 16B-positions) into LDS.
// LDS layout is LINEAR for global_load_lds (base + lane*16); the bank-conflict
// swizzle is applied by permuting the GLOBAL source slot (rule #21):
//   physical slot sp at row r holds logical k-slot sl = sp ^ (r&7).
// Readers XOR their slot the same way -> conflict-free ds_read_b128.
// g_row0: element pointer to row 0 of the tile; kk0: k-element base of this BK slice.
__device__ __forceinline__ void stage_tile(const short* __restrict__ g_row0,
                                           char* lds_base, int t, int kk0) {
#pragma unroll
  for (int c = 0; c < 4; ++c) {
    int p = c * 256 + t;              // 16B position 0..1023
    int r = p >> 3;                   // LDS row 0..127
    int sl = (p & 7) ^ (r & 7);       // logical k-slot (8 bf16 each)
    async_ld16(g_row0 + (size_t)r * D_ + kk0 + sl * 8, lds_base + p * 16);
  }
}

// ---------------- K0: UT[n][k] = bf16(U[k][n]) ----------------
__global__ void k_prep_u(const float* __restrict__ U, short* __restrict__ UT) {
  int n = blockIdx.x;
  int k = threadIdx.x;
  UT[n * D_ + k] = bf16of(U[k * D_ + n]);
}

// ---- K_rows: hs = head@wh, ds = dep@wd (fp32 exact); headB/depB = bf16(X) ----
__global__ void k_rows(const float* __restrict__ head, const float* __restrict__ dep,
                       const float* __restrict__ W,
                       float* __restrict__ hs, float* __restrict__ ds,
                       short* __restrict__ headB, short* __restrict__ depB) {
  const float* X; const float* wv; float* sv; short* XB;
  if (blockIdx.y == 0) { X = head; wv = W;      sv = hs; XB = headB; }
  else                 { X = dep;  wv = W + D_; sv = ds; XB = depB;  }
  const int row = blockIdx.x * 4 + (threadIdx.x >> 6);
  const int l = threadIdx.x & 63;
  const float4 v  = *(const float4*)(X + (size_t)row * D_ + l * 4);
  const float4 wq = *(const float4*)(wv + l * 4);
  short4v pk;
  pk[0] = bf16of(v.x); pk[1] = bf16of(v.y); pk[2] = bf16of(v.z); pk[3] = bf16of(v.w);
  *(short4v*)(XB + (size_t)row * D_ + l * 4) = pk;
  float p = v.x * wq.x + v.y * wq.y + v.z * wq.z + v.w * wq.w;
  p += __shfl_xor(p, 1); p += __shfl_xor(p, 2); p += __shfl_xor(p, 4);
  p += __shfl_xor(p, 8); p += __shfl_xor(p, 16); p += __shfl_xor(p, 32);
  if (l == 0) sv[row] = p;
}

// ---------------- K1: Ahat = headB @ U (bf16) ----------------
// Staged, swizzled LDS, counted-vmcnt double buffer. BK=64, 4 K-steps.
// A-operand = UT rows (m = n_col), B-operand = headB rows (n = i).
__launch_bounds__(256, 2)
__global__ void k_ahat(const short* __restrict__ headB, const short* __restrict__ UT,
                       short* __restrict__ Ahat) {
  __shared__ __align__(16) short sU[2 * 128 * 64];  // 32 KB (2 buffers)
  __shared__ __align__(16) short sH[2 * 128 * 64];  // 32 KB
  const int t = threadIdx.x;
  const int w = t >> 6;
  const int l = t & 63;
  const int quad = l >> 4;
  const int r15 = l & 15;
  const int sw = r15 & 7;                // read-side slot swizzle
  const int nbase = blockIdx.x * 128;
  const int mbase = blockIdx.y * 128;

  const short* gA = UT + (size_t)nbase * D_;
  const short* gB = headB + (size_t)mbase * D_;

  f32x4 acc[4][4];
#pragma unroll
  for (int i = 0; i < 4; ++i)
#pragma unroll
    for (int j = 0; j < 4; ++j) acc[i][j] = (f32x4)0.0f;

  // prologue: fill both buffers (8 issues per wave per buffer)
  stage_tile(gA, (char*)sU, t, 0);
  stage_tile(gB, (char*)sH, t, 0);
  stage_tile(gA, (char*)sU + 16384, t, 64);
  stage_tile(gB, (char*)sH + 16384, t, 64);

  const int baseA = ((w >> 1) * 64 + r15) * 8;
  const int baseB = ((w & 1) * 64 + r15) * 8;

#pragma unroll
  for (int it = 0; it < 4; ++it) {
    if (it < 3) asm volatile("s_waitcnt vmcnt(8)" ::: "memory");
    else        asm volatile("s_waitcnt vmcnt(0)" ::: "memory");
    __builtin_amdgcn_s_barrier();

    const short8* pA = (const short8*)(sU + (size_t)(it & 1) * (128 * 64));
    const short8* pB = (const short8*)(sH + (size_t)(it & 1) * (128 * 64));
#pragma unroll
    for (int kb = 0; kb < 2; ++kb) {
      const int so = (kb * 4 + quad) ^ sw;
      short8 aF[4], bF[4];
#pragma unroll
      for (int mt = 0; mt < 4; ++mt) aF[mt] = pA[baseA + mt * 128 + so];
#pragma unroll
      for (int nt = 0; nt < 4; ++nt) bF[nt] = pB[baseB + nt * 128 + so];
#pragma unroll
      for (int mt = 0; mt < 4; ++mt)
#pragma unroll
        for (int nt = 0; nt < 4; ++nt)
          acc[mt][nt] = __builtin_amdgcn_mfma_f32_16x16x32_bf16(aF[mt], bF[nt], acc[mt][nt], 0, 0, 0);
    }
    __builtin_amdgcn_s_barrier();      // all waves done reading buf[it&1]
    if (it < 2) {                      // refill the buffer just consumed
      stage_tile(gA, (char*)sU + (size_t)(it & 1) * 16384, t, (it + 2) * 64);
      stage_tile(gB, (char*)sH + (size_t)(it & 1) * 16384, t, (it + 2) * 64);
    }
  }

  // D[m=n_col][n=i] -> lane holds 4 consecutive n_col for fixed i: short4 stores
#pragma unroll
  for (int mt = 0; mt < 4; ++mt) {
    int n_loc = (w >> 1) * 64 + mt * 16 + quad * 4;
#pragma unroll
    for (int nt = 0; nt < 4; ++nt) {
      int i_loc = (w & 1) * 64 + nt * 16 + r15;
      short4v pk;
      pk[0] = bf16of(acc[mt][nt][0]); pk[1] = bf16of(acc[mt][nt][1]);
      pk[2] = bf16of(acc[mt][nt][2]); pk[3] = bf16of(acc[mt][nt][3]);
      *(short4v*)(Ahat + (size_t)(mbase + i_loc) * D_ + nbase + n_loc) = pk;
    }
  }
}

// ------- K2: out[b,i,o] = sum_k Ahat[b,i,k] depB[b,o,k] + hs[i] + ds[o] + bias -------
// grid (16 o-tiles, 16 i-tiles, 8 b); A-operand = depB (m = o), B-operand = Ahat (n = i)
// Staged, swizzled LDS, counted-vmcnt double buffer. BK=64, 4 K-steps.
__launch_bounds__(256, 2)
__global__ void k_main(const short* __restrict__ Ahat, const short* __restrict__ depB,
                       const float* __restrict__ hs, const float* __restrict__ ds,
                       const float* __restrict__ eb, float* __restrict__ out) {
  __shared__ __align__(16) short sD[2 * 128 * 64];   // 32 KB: depB rows (o)
  __shared__ __align__(16) short sAh[2 * 128 * 64];  // 32 KB: Ahat rows (i)
  const int t = threadIdx.x;
  const int w = t >> 6;
  const int l = t & 63;
  const int quad = l >> 4;
  const int r15 = l & 15;
  const int sw = r15 & 7;
  const int b = blockIdx.z;
  const int mbase = blockIdx.y * 128;  // i
  const int nbase = blockIdx.x * 128;  // o

  const short* gA = depB + (size_t)(b * S_ + nbase) * D_;
  const short* gB = Ahat + (size_t)(b * S_ + mbase) * D_;

  f32x4 acc[4][4];
#pragma unroll
  for (int i = 0; i < 4; ++i)
#pragma unroll
    for (int j = 0; j < 4; ++j) acc[i][j] = (f32x4)0.0f;

  stage_tile(gA, (char*)sD, t, 0);
  stage_tile(gB, (char*)sAh, t, 0);
  stage_tile(gA, (char*)sD + 16384, t, 64);
  stage_tile(gB, (char*)sAh + 16384, t, 64);

  const int baseA = ((w >> 1) * 64 + r15) * 8;
  const int baseB = ((w & 1) * 64 + r15) * 8;

#pragma unroll
  for (int it = 0; it < 4; ++it) {
    if (it < 3) asm volatile("s_waitcnt vmcnt(8)" ::: "memory");
    else        asm volatile("s_waitcnt vmcnt(0)" ::: "memory");
    __builtin_amdgcn_s_barrier();

    const short8* pA = (const short8*)(sD + (size_t)(it & 1) * (128 * 64));
    const short8* pB = (const short8*)(sAh + (size_t)(it & 1) * (128 * 64));
#pragma unroll
    for (int kb = 0; kb < 2; ++kb) {
      const int so = (kb * 4 + quad) ^ sw;
      short8 aF[4], bF[4];
#pragma unroll
      for (int mt = 0; mt < 4; ++mt) aF[mt] = pA[baseA + mt * 128 + so];
#pragma unroll
      for (int nt = 0; nt < 4; ++nt) bF[nt] = pB[baseB + nt * 128 + so];
#pragma unroll
      for (int mt = 0; mt < 4; ++mt)
#pragma unroll
        for (int nt = 0; nt < 4; ++nt)
          acc[mt][nt] = __builtin_amdgcn_mfma_f32_16x16x32_bf16(aF[mt], bF[nt], acc[mt][nt], 0, 0, 0);
    }
    __builtin_amdgcn_s_barrier();
    if (it < 2) {
      stage_tile(gA, (char*)sD + (size_t)(it & 1) * 16384, t, (it + 2) * 64);
      stage_tile(gB, (char*)sAh + (size_t)(it & 1) * 16384, t, (it + 2) * 64);
    }
  }

  const float bias = eb[0];
  float hv4[4];
#pragma unroll
  for (int nt = 0; nt < 4; ++nt)
    hv4[nt] = hs[(size_t)b * S_ + mbase + (w & 1) * 64 + nt * 16 + r15] + bias;

#pragma unroll
  for (int mt = 0; mt < 4; ++mt) {
    int o_loc = (w >> 1) * 64 + mt * 16 + quad * 4;
    float4 dsv = *(const float4*)(ds + (size_t)b * S_ + nbase + o_loc);
#pragma unroll
    for (int nt = 0; nt < 4; ++nt) {
      int i_loc = (w & 1) * 64 + nt * 16 + r15;
      float hv = hv4[nt];
      f32x4 a = acc[mt][nt];
      float4 o4;
      o4.x = a[0] + hv + dsv.x;
      o4.y = a[1] + hv + dsv.y;
      o4.z = a[2] + hv + dsv.z;
      o4.w = a[3] + hv + dsv.w;
      *(float4*)(out + (size_t)(b * S_ + mbase + i_loc) * S_ + nbase + o_loc) = o4;
    }
  }
}

extern "C" void kernel_launch(void* const* d_in, const int* in_sizes, int n_in,
                              void* d_out, int out_size, void* d_ws, size_t ws_size,
                              hipStream_t stream) {
  const float* head = (const float*)d_in[0];
  const float* dep  = (const float*)d_in[1];
  const float* U    = (const float*)d_in[2];
  const float* W    = (const float*)d_in[3];  // (1, 512): wh | wd
  const float* eb   = (const float*)d_in[4];
  float* out = (float*)d_out;

  char* ws = (char*)d_ws;
  short* UT    = (short*)ws;                       // 256*256*2     = 128 KB
  float* hs    = (float*)(ws + (128 << 10));       // 16384*4       = 64 KB
  float* ds    = (float*)(ws + (192 << 10));       // 16384*4       = 64 KB
  short* headB = (short*)(ws + (256 << 10));       // 16384*256*2   = 8 MB
  short* depB  = (short*)(ws + (256 << 10) + (8 << 20));
  short* Ahat  = (short*)(ws + (256 << 10) + (16 << 20));

  k_prep_u<<<dim3(256), dim3(256), 0, stream>>>(U, UT);
  k_rows<<<dim3(NROWS / 4, 2), dim3(256), 0, stream>>>(head, dep, W, hs, ds, headB, depB);
  k_ahat<<<dim3(2, 128), dim3(256), 0, stream>>>(headB, UT, Ahat);
  k_main<<<dim3(16, 16, 8), dim3(256), 0, stream>>>(Ahat, depB, hs, ds, eb, out);
}